// Round 1
// baseline (1182.176 us; speedup 1.0000x reference)
//
#include <hip/hip_runtime.h>

// ---------------------------------------------------------------------------
// GCN: 5 x (GEMM -> gather-aggregate) + mean-pool + 3-layer MLP.
// CSR-by-dst built per launch so aggregation is an atomic-free gather.
// hs = (x @ W) * dinv[row];  out = relu(dinv[i]*(hs[i] + sum_src hs[src]) + b)
// ---------------------------------------------------------------------------

static constexpr int TPB = 256;

__global__ void k_count(const int* __restrict__ dst, int* __restrict__ cnt, int E) {
    int e = blockIdx.x * blockDim.x + threadIdx.x;
    if (e < E) atomicAdd(&cnt[dst[e]], 1);
}

__global__ void k_scanA(const int* __restrict__ cnt, int* __restrict__ rowptr,
                        int* __restrict__ bsum, int n) {
    __shared__ int s[TPB];
    int t = threadIdx.x;
    int i = blockIdx.x * TPB + t;
    s[t] = (i < n) ? cnt[i] : 0;
    __syncthreads();
    for (int off = 1; off < TPB; off <<= 1) {
        int add = (t >= off) ? s[t - off] : 0;
        __syncthreads();
        s[t] += add;
        __syncthreads();
    }
    if (i < n) rowptr[i + 1] = s[t];
    if (t == TPB - 1) bsum[blockIdx.x] = s[t];
}

__global__ void k_scanB(const int* __restrict__ bsum, int* __restrict__ bscan, int nb) {
    __shared__ int s[512];
    int t = threadIdx.x;
    s[t] = (t < nb) ? bsum[t] : 0;
    __syncthreads();
    for (int off = 1; off < 512; off <<= 1) {
        int add = (t >= off) ? s[t - off] : 0;
        __syncthreads();
        s[t] += add;
        __syncthreads();
    }
    if (t < nb) bscan[t] = (t > 0) ? s[t - 1] : 0;
}

__global__ void k_scanC(int* __restrict__ rowptr, const int* __restrict__ bscan, int n) {
    int i = blockIdx.x * blockDim.x + threadIdx.x;
    if (i < n) rowptr[i + 1] += bscan[i >> 8];
    if (i == 0) rowptr[0] = 0;
}

__global__ void k_dinv(const int* __restrict__ cnt, float* __restrict__ dinv, int n) {
    int i = blockIdx.x * blockDim.x + threadIdx.x;
    if (i < n) dinv[i] = 1.0f / sqrtf((float)cnt[i] + 1.0f);
}

__global__ void k_fill(const int* __restrict__ src, const int* __restrict__ dst,
                       const int* __restrict__ rowptr, int* __restrict__ fillc,
                       int* __restrict__ csr, int E) {
    int e = blockIdx.x * blockDim.x + threadIdx.x;
    if (e >= E) return;
    int d = dst[e];
    int p = atomicAdd(&fillc[d], 1);
    csr[rowptr[d] + p] = src[e];
}

// GEMM: hs[r][c] = dinv[r] * sum_k xin[r][k] * W[k][c]
// 2 rows x 16 cols per thread, W staged in LDS.
template <int K, int OUT>
__global__ __launch_bounds__(256) void k_gemm(const float* __restrict__ xin,
                                              const float* __restrict__ W,
                                              const float* __restrict__ dinv,
                                              float* __restrict__ hs, int n) {
    static_assert(OUT % 16 == 0 && K % 4 == 0, "");
    constexpr int CG = OUT / 16;          // col groups of 16
    constexpr int RPB = 512 / CG;         // rows per block (2 rows/thread)
    __shared__ float Wlds[K * OUT];
    int t = threadIdx.x;
    for (int i = t; i < K * OUT / 4; i += 256)
        ((float4*)Wlds)[i] = ((const float4*)W)[i];
    __syncthreads();

    int cg = t % CG;
    int rl = t / CG;
    int r0 = blockIdx.x * RPB + rl * 2;
    if (r0 >= n) return;
    int r1 = r0 + 1;
    bool w1 = (r1 < n);
    const float4* x0 = (const float4*)(xin + (size_t)r0 * K);
    const float4* x1 = (const float4*)(xin + (size_t)(w1 ? r1 : r0) * K);

    float acc0[16], acc1[16];
#pragma unroll
    for (int c = 0; c < 16; ++c) { acc0[c] = 0.f; acc1[c] = 0.f; }

    for (int k4 = 0; k4 < K / 4; ++k4) {
        float4 xa = x0[k4];
        float4 xb = x1[k4];
        float xav[4] = {xa.x, xa.y, xa.z, xa.w};
        float xbv[4] = {xb.x, xb.y, xb.z, xb.w};
#pragma unroll
        for (int u = 0; u < 4; ++u) {
            const float* wr = &Wlds[(k4 * 4 + u) * OUT + cg * 16];
            float a = xav[u], b = xbv[u];
#pragma unroll
            for (int c = 0; c < 16; ++c) {
                float wv = wr[c];
                acc0[c] += a * wv;
                acc1[c] += b * wv;
            }
        }
    }

    float d0 = dinv[r0];
    float d1 = w1 ? dinv[r1] : 0.f;
    float4* o0 = (float4*)(hs + (size_t)r0 * OUT + cg * 16);
    float4* o1 = (float4*)(hs + (size_t)r1 * OUT + cg * 16);
#pragma unroll
    for (int q = 0; q < 4; ++q) {
        float4 v;
        v.x = acc0[q * 4 + 0] * d0; v.y = acc0[q * 4 + 1] * d0;
        v.z = acc0[q * 4 + 2] * d0; v.w = acc0[q * 4 + 3] * d0;
        o0[q] = v;
        if (w1) {
            float4 u;
            u.x = acc1[q * 4 + 0] * d1; u.y = acc1[q * 4 + 1] * d1;
            u.z = acc1[q * 4 + 2] * d1; u.w = acc1[q * 4 + 3] * d1;
            o1[q] = u;
        }
    }
}

// Gather: out[i] = (relu?) dinv[i]*(hs[i] + sum_{src in csr[i]} hs[src]) + b
template <int D, bool RELU>
__global__ __launch_bounds__(256) void k_gather(const float* __restrict__ hs,
                                                const int* __restrict__ rowptr,
                                                const int* __restrict__ csr,
                                                const float* __restrict__ dinv,
                                                const float* __restrict__ bias,
                                                float* __restrict__ out, int n) {
    constexpr int TPN = D / 4;  // threads per node
    int gid = blockIdx.x * blockDim.x + threadIdx.x;
    int node = gid / TPN;
    if (node >= n) return;
    int c4 = gid % TPN;
    const float4* hs4 = (const float4*)hs;
    float4 acc = hs4[(size_t)node * TPN + c4];
    int j0 = rowptr[node], j1 = rowptr[node + 1];
    for (int j = j0; j < j1; ++j) {
        int s = csr[j];
        float4 v = hs4[(size_t)s * TPN + c4];
        acc.x += v.x; acc.y += v.y; acc.z += v.z; acc.w += v.w;
    }
    float di = dinv[node];
    float4 bb = ((const float4*)bias)[c4];
    float4 r;
    r.x = di * acc.x + bb.x;
    r.y = di * acc.y + bb.y;
    r.z = di * acc.z + bb.z;
    r.w = di * acc.w + bb.w;
    if (RELU) {
        r.x = fmaxf(r.x, 0.f); r.y = fmaxf(r.y, 0.f);
        r.z = fmaxf(r.z, 0.f); r.w = fmaxf(r.w, 0.f);
    }
    ((float4*)out)[(size_t)node * TPN + c4] = r;
}

// Mean pool per graph (batch sorted). One block per graph.
__global__ __launch_bounds__(256) void k_pool(const float* __restrict__ h,
                                              const int* __restrict__ batch,
                                              float* __restrict__ g, int n) {
    __shared__ int se[2];
    __shared__ float red[8][32];
    int gi = blockIdx.x;
    int t = threadIdx.x;
    if (t == 0) {
        int lo = 0, hi = n;
        while (lo < hi) { int m = (lo + hi) >> 1; if (batch[m] < gi) lo = m + 1; else hi = m; }
        se[0] = lo;
        lo = 0; hi = n;
        while (lo < hi) { int m = (lo + hi) >> 1; if (batch[m] < gi + 1) lo = m + 1; else hi = m; }
        se[1] = lo;
    }
    __syncthreads();
    int start = se[0], end = se[1];
    int col = t & 31, sub = t >> 5;
    float acc = 0.f;
    for (int i = start + sub; i < end; i += 8)
        acc += h[(size_t)i * 32 + col];
    red[sub][col] = acc;
    __syncthreads();
    if (t < 32) {
        float s = 0.f;
#pragma unroll
        for (int q = 0; q < 8; ++q) s += red[q][t];
        float c = (float)(end - start);
        g[gi * 32 + t] = s / fmaxf(c, 1.0f);
    }
}

template <int K, int O, bool RELU>
__global__ void k_mlp(const float* __restrict__ in, const float* __restrict__ W,
                      const float* __restrict__ b, float* __restrict__ out, int G) {
    int gid = blockIdx.x * blockDim.x + threadIdx.x;
    if (gid >= G * O) return;
    int g = gid / O, j = gid % O;
    float s = b[j];
    for (int k = 0; k < K; ++k) s += in[g * K + k] * W[k * O + j];
    if (RELU) s = fmaxf(s, 0.f);
    out[gid] = s;
}

extern "C" void kernel_launch(void* const* d_in, const int* in_sizes, int n_in,
                              void* d_out, int out_size, void* d_ws, size_t ws_size,
                              hipStream_t stream) {
    const float* x    = (const float*)d_in[0];
    const int*   ei   = (const int*)d_in[1];
    const int*   batch= (const int*)d_in[2];
    const float* W1 = (const float*)d_in[3];  const float* b1 = (const float*)d_in[4];
    const float* W2 = (const float*)d_in[5];  const float* b2 = (const float*)d_in[6];
    const float* W3 = (const float*)d_in[7];  const float* b3 = (const float*)d_in[8];
    const float* W4 = (const float*)d_in[9];  const float* b4 = (const float*)d_in[10];
    const float* Wo = (const float*)d_in[11]; const float* bo = (const float*)d_in[12];
    const float* M1w = (const float*)d_in[13]; const float* M1b = (const float*)d_in[14];
    const float* M2w = (const float*)d_in[15]; const float* M2b = (const float*)d_in[16];
    const float* M3w = (const float*)d_in[17]; const float* M3b = (const float*)d_in[18];

    const int N = in_sizes[0] / 64;   // 100000
    const int E = in_sizes[1] / 2;    // 1600000
    const int G = out_size / 8;       // 64
    const int* src  = ei;
    const int* dstp = ei + E;

    char* w = (char*)d_ws;
    float* A      = (float*)w; w += (size_t)N * 128 * 4;
    float* B      = (float*)w; w += (size_t)N * 128 * 4;
    int*   csr    = (int*)w;   w += (size_t)E * 4;
    int*   cnt    = (int*)w;   w += (size_t)N * 4;
    int*   rowptr = (int*)w;   w += (size_t)(N + 4) * 4;
    int*   fillc  = (int*)w;   w += (size_t)N * 4;
    int*   bsum   = (int*)w;   w += 4096;
    int*   bscan  = (int*)w;   w += 4096;
    float* dinv   = (float*)w; w += (size_t)N * 4;
    float* gp     = (float*)w; w += 64 * 32 * 4;
    float* m1     = (float*)w; w += 64 * 64 * 4;
    float* m2     = (float*)w; w += 64 * 16 * 4;

    const int NB = (N + TPB - 1) / TPB;
    const int EB = (E + TPB - 1) / TPB;

    hipMemsetAsync(cnt, 0, (size_t)N * 4, stream);
    hipMemsetAsync(fillc, 0, (size_t)N * 4, stream);
    k_count<<<EB, TPB, 0, stream>>>(dstp, cnt, E);
    k_scanA<<<NB, TPB, 0, stream>>>(cnt, rowptr, bsum, N);
    k_scanB<<<1, 512, 0, stream>>>(bsum, bscan, NB);
    k_scanC<<<NB, TPB, 0, stream>>>(rowptr, bscan, N);
    k_dinv<<<NB, TPB, 0, stream>>>(cnt, dinv, N);
    k_fill<<<EB, TPB, 0, stream>>>(src, dstp, rowptr, fillc, csr, E);

    // Layer 1: 64 -> 128
    k_gemm<64, 128><<<(N + 63) / 64, 256, 0, stream>>>(x, W1, dinv, B, N);
    k_gather<128, true><<<(N * 32 + 255) / 256, 256, 0, stream>>>(B, rowptr, csr, dinv, b1, A, N);
    // Layers 2-4: 128 -> 128
    k_gemm<128, 128><<<(N + 63) / 64, 256, 0, stream>>>(A, W2, dinv, B, N);
    k_gather<128, true><<<(N * 32 + 255) / 256, 256, 0, stream>>>(B, rowptr, csr, dinv, b2, A, N);
    k_gemm<128, 128><<<(N + 63) / 64, 256, 0, stream>>>(A, W3, dinv, B, N);
    k_gather<128, true><<<(N * 32 + 255) / 256, 256, 0, stream>>>(B, rowptr, csr, dinv, b3, A, N);
    k_gemm<128, 128><<<(N + 63) / 64, 256, 0, stream>>>(A, W4, dinv, B, N);
    k_gather<128, true><<<(N * 32 + 255) / 256, 256, 0, stream>>>(B, rowptr, csr, dinv, b4, A, N);
    // Layer 5: 128 -> 32 (no relu)
    k_gemm<128, 32><<<(N + 255) / 256, 256, 0, stream>>>(A, Wo, dinv, B, N);
    k_gather<32, false><<<(N * 8 + 255) / 256, 256, 0, stream>>>(B, rowptr, csr, dinv, bo, A, N);

    // Mean pool + MLP head
    k_pool<<<G, 256, 0, stream>>>(A, batch, gp, N);
    k_mlp<32, 64, true><<<(G * 64 + 255) / 256, 256, 0, stream>>>(gp, M1w, M1b, m1, G);
    k_mlp<64, 16, true><<<(G * 16 + 255) / 256, 256, 0, stream>>>(m1, M2w, M2b, m2, G);
    k_mlp<16, 8, false><<<(G * 8 + 255) / 256, 256, 0, stream>>>(m2, M3w, M3b, (float*)d_out, G);
}

// Round 2
// 869.716 us; speedup vs baseline: 1.3593x; 1.3593x over previous
//
#include <hip/hip_runtime.h>

// ---------------------------------------------------------------------------
// GCN: CSR-by-dst build + 5 x (GEMM / gather-aggregate) + mean-pool + MLP.
// Neighbor tables stored bf16 (RNE), all accumulation and weights fp32.
// Layer 1 is aggregate-first (64-dim), layers 2-5 GEMM-first.
//   hs = (A @ W) * dinv_src  (bf16)
//   out_i = relu(dinv_i * (hs_i + sum_{j->i} hs_j) + b)
// ---------------------------------------------------------------------------

static constexpr int TPB = 256;

__device__ __forceinline__ float u2f(unsigned u) { return __uint_as_float(u); }

// pack two fp32 -> two bf16 (RNE) in one uint
__device__ __forceinline__ unsigned bf2(float a, float b) {
    unsigned ua = __float_as_uint(a);
    unsigned ub = __float_as_uint(b);
    ua += 0x7FFFu + ((ua >> 16) & 1u);
    ub += 0x7FFFu + ((ub >> 16) & 1u);
    return (ua >> 16) | (ub & 0xFFFF0000u);
}

// ------------------------------- CSR build ---------------------------------
__global__ void k_count(const int* __restrict__ dst, int* __restrict__ cnt, int E) {
    int e = blockIdx.x * blockDim.x + threadIdx.x;
    if (e < E) atomicAdd(&cnt[dst[e]], 1);
}

__global__ void k_scanA(const int* __restrict__ cnt, int* __restrict__ rowptr,
                        int* __restrict__ bsum, int n) {
    __shared__ int s[TPB];
    int t = threadIdx.x;
    int i = blockIdx.x * TPB + t;
    s[t] = (i < n) ? cnt[i] : 0;
    __syncthreads();
    for (int off = 1; off < TPB; off <<= 1) {
        int add = (t >= off) ? s[t - off] : 0;
        __syncthreads();
        s[t] += add;
        __syncthreads();
    }
    if (i < n) rowptr[i + 1] = s[t];
    if (t == TPB - 1) bsum[blockIdx.x] = s[t];
}

__global__ void k_scanB(const int* __restrict__ bsum, int* __restrict__ bscan, int nb) {
    __shared__ int s[512];
    int t = threadIdx.x;
    s[t] = (t < nb) ? bsum[t] : 0;
    __syncthreads();
    for (int off = 1; off < 512; off <<= 1) {
        int add = (t >= off) ? s[t - off] : 0;
        __syncthreads();
        s[t] += add;
        __syncthreads();
    }
    if (t < nb) bscan[t] = (t > 0) ? s[t - 1] : 0;
}

__global__ void k_scanC(int* __restrict__ rowptr, const int* __restrict__ bscan, int n) {
    int i = blockIdx.x * blockDim.x + threadIdx.x;
    if (i < n) rowptr[i + 1] += bscan[i >> 8];
    if (i == 0) rowptr[0] = 0;
}

__global__ void k_dinv(const int* __restrict__ cnt, float* __restrict__ dinv, int n) {
    int i = blockIdx.x * blockDim.x + threadIdx.x;
    if (i < n) dinv[i] = 1.0f / sqrtf((float)cnt[i] + 1.0f);
}

__global__ void k_fill(const int* __restrict__ src, const int* __restrict__ dst,
                       const int* __restrict__ rowptr, int* __restrict__ fillc,
                       int* __restrict__ csr, int E) {
    int e = blockIdx.x * blockDim.x + threadIdx.x;
    if (e >= E) return;
    int d = dst[e];
    int p = atomicAdd(&fillc[d], 1);
    csr[rowptr[d] + p] = src[e];
}

// xs[i,k] = bf16(x[i,k] * dinv[i]); 8 elems/thread
__global__ void k_castx(const float* __restrict__ x, const float* __restrict__ dinv,
                        unsigned short* __restrict__ xs, int n) {
    int gid = blockIdx.x * blockDim.x + threadIdx.x;  // per 8 elements, 8 groups/row
    if (gid >= n * 8) return;
    int row = gid >> 3;
    float d = dinv[row];
    const float4* xp = (const float4*)x + (size_t)gid * 2;
    float4 a = xp[0], b = xp[1];
    uint4 o;
    o.x = bf2(a.x * d, a.y * d);
    o.y = bf2(a.z * d, a.w * d);
    o.z = bf2(b.x * d, b.y * d);
    o.w = bf2(b.z * d, b.w * d);
    ((uint4*)xs)[gid] = o;
}

// ------------------------------- GEMM --------------------------------------
// EPI 0: out = bf16(acc * dinv[row])            (feeds gather)
// EPI 1: out = fp32 relu(acc + bias)            (layer-1 output)
template <int K, int OUT, int EPI>
__global__ __launch_bounds__(256) void k_gemm(const float* __restrict__ xin,
                                              const float* __restrict__ W,
                                              const float* __restrict__ dinv,
                                              const float* __restrict__ bias,
                                              void* __restrict__ outp, int n) {
    constexpr int CG = OUT / 16;           // threads per row-group
    constexpr int R = (OUT <= 32) ? 2 : 4; // rows per thread
    constexpr int ROWS = (256 / CG) * R;   // rows per block
    constexpr int KC = 32;                 // K chunk staged in LDS
    constexpr int QS = OUT / 4;            // col-group stride (bank-conflict-free)
    __shared__ float Wl[KC * OUT];

    int t = threadIdx.x;
    int cg = t % CG;
    int rl = t / CG;
    int r0 = blockIdx.x * ROWS + rl * R;

    float acc[R][16];
#pragma unroll
    for (int r = 0; r < R; ++r)
#pragma unroll
        for (int c = 0; c < 16; ++c) acc[r][c] = 0.f;

    const float4* W4 = (const float4*)W;
    const float4* xp[R];
    int rows[R];
    bool val[R];
#pragma unroll
    for (int r = 0; r < R; ++r) {
        rows[r] = r0 + r;
        val[r] = rows[r] < n;
        int rr = val[r] ? rows[r] : (n - 1);
        xp[r] = (const float4*)(xin + (size_t)rr * K);
    }

    for (int kc = 0; kc < K / KC; ++kc) {
        __syncthreads();
        for (int i = t; i < KC * OUT / 4; i += 256)
            ((float4*)Wl)[i] = W4[kc * (KC * OUT / 4) + i];
        __syncthreads();
#pragma unroll
        for (int k4 = 0; k4 < KC / 4; ++k4) {
            float4 xr[R];
#pragma unroll
            for (int r = 0; r < R; ++r) xr[r] = xp[r][kc * (KC / 4) + k4];
#pragma unroll
            for (int u = 0; u < 4; ++u) {
                float4 wq[4];
#pragma unroll
                for (int q = 0; q < 4; ++q)
                    wq[q] = *(const float4*)&Wl[(k4 * 4 + u) * OUT + cg * 4 + q * QS];
#pragma unroll
                for (int r = 0; r < R; ++r) {
                    float a = (u == 0) ? xr[r].x : (u == 1) ? xr[r].y
                                                : (u == 2) ? xr[r].z : xr[r].w;
#pragma unroll
                    for (int q = 0; q < 4; ++q) {
                        acc[r][q * 4 + 0] += a * wq[q].x;
                        acc[r][q * 4 + 1] += a * wq[q].y;
                        acc[r][q * 4 + 2] += a * wq[q].z;
                        acc[r][q * 4 + 3] += a * wq[q].w;
                    }
                }
            }
        }
    }

    if (EPI == 0) {
        unsigned short* ob = (unsigned short*)outp;
#pragma unroll
        for (int r = 0; r < R; ++r) {
            if (!val[r]) continue;
            float d = dinv[rows[r]];
#pragma unroll
            for (int q = 0; q < 4; ++q) {
                uint2 p;
                p.x = bf2(acc[r][q * 4 + 0] * d, acc[r][q * 4 + 1] * d);
                p.y = bf2(acc[r][q * 4 + 2] * d, acc[r][q * 4 + 3] * d);
                *(uint2*)(ob + (size_t)rows[r] * OUT + cg * 4 + q * QS) = p;
            }
        }
    } else {
        float* of = (float*)outp;
        float4 bq[4];
#pragma unroll
        for (int q = 0; q < 4; ++q) bq[q] = *(const float4*)&bias[cg * 4 + q * QS];
#pragma unroll
        for (int r = 0; r < R; ++r) {
            if (!val[r]) continue;
#pragma unroll
            for (int q = 0; q < 4; ++q) {
                float4 v;
                v.x = fmaxf(acc[r][q * 4 + 0] + bq[q].x, 0.f);
                v.y = fmaxf(acc[r][q * 4 + 1] + bq[q].y, 0.f);
                v.z = fmaxf(acc[r][q * 4 + 2] + bq[q].z, 0.f);
                v.w = fmaxf(acc[r][q * 4 + 3] + bq[q].w, 0.f);
                *(float4*)&of[(size_t)rows[r] * OUT + cg * 4 + q * QS] = v;
            }
        }
    }
}

// --------------------------- gather (bf16 table) ---------------------------
// out_i = [relu]( dinv_i * (hs_i + sum_j hs_j) [+ bias] )   fp32 out
template <int D, bool RELU, bool HASBIAS>
__global__ __launch_bounds__(256) void k_gather_bf(const unsigned short* __restrict__ hsb,
                                                   const int* __restrict__ rowptr,
                                                   const int* __restrict__ csr,
                                                   const float* __restrict__ dinv,
                                                   const float* __restrict__ bias,
                                                   float* __restrict__ out, int n) {
    constexpr int TPN = D / 8;  // threads per node, 8 bf16 (16B) each
    int gid = blockIdx.x * blockDim.x + threadIdx.x;
    int node = gid / TPN;
    if (node >= n) return;
    int c = gid % TPN;
    const uint4* hb = (const uint4*)hsb;

    float acc[8];
    {
        uint4 v = hb[(size_t)node * TPN + c];
        acc[0] = u2f(v.x << 16); acc[1] = u2f(v.x & 0xFFFF0000u);
        acc[2] = u2f(v.y << 16); acc[3] = u2f(v.y & 0xFFFF0000u);
        acc[4] = u2f(v.z << 16); acc[5] = u2f(v.z & 0xFFFF0000u);
        acc[6] = u2f(v.w << 16); acc[7] = u2f(v.w & 0xFFFF0000u);
    }
    int j0 = rowptr[node], j1 = rowptr[node + 1];
    int j = j0;
    for (; j + 1 < j1; j += 2) {  // unroll-2 for memory-level parallelism
        uint4 w0 = hb[(size_t)csr[j] * TPN + c];
        uint4 w1 = hb[(size_t)csr[j + 1] * TPN + c];
        acc[0] += u2f(w0.x << 16); acc[1] += u2f(w0.x & 0xFFFF0000u);
        acc[2] += u2f(w0.y << 16); acc[3] += u2f(w0.y & 0xFFFF0000u);
        acc[4] += u2f(w0.z << 16); acc[5] += u2f(w0.z & 0xFFFF0000u);
        acc[6] += u2f(w0.w << 16); acc[7] += u2f(w0.w & 0xFFFF0000u);
        acc[0] += u2f(w1.x << 16); acc[1] += u2f(w1.x & 0xFFFF0000u);
        acc[2] += u2f(w1.y << 16); acc[3] += u2f(w1.y & 0xFFFF0000u);
        acc[4] += u2f(w1.z << 16); acc[5] += u2f(w1.z & 0xFFFF0000u);
        acc[6] += u2f(w1.w << 16); acc[7] += u2f(w1.w & 0xFFFF0000u);
    }
    if (j < j1) {
        uint4 w0 = hb[(size_t)csr[j] * TPN + c];
        acc[0] += u2f(w0.x << 16); acc[1] += u2f(w0.x & 0xFFFF0000u);
        acc[2] += u2f(w0.y << 16); acc[3] += u2f(w0.y & 0xFFFF0000u);
        acc[4] += u2f(w0.z << 16); acc[5] += u2f(w0.z & 0xFFFF0000u);
        acc[6] += u2f(w0.w << 16); acc[7] += u2f(w0.w & 0xFFFF0000u);
    }

    float di = dinv[node];
    float r[8];
    if (HASBIAS) {
        float4 b0 = *(const float4*)&bias[c * 8];
        float4 b1 = *(const float4*)&bias[c * 8 + 4];
        r[0] = di * acc[0] + b0.x; r[1] = di * acc[1] + b0.y;
        r[2] = di * acc[2] + b0.z; r[3] = di * acc[3] + b0.w;
        r[4] = di * acc[4] + b1.x; r[5] = di * acc[5] + b1.y;
        r[6] = di * acc[6] + b1.z; r[7] = di * acc[7] + b1.w;
    } else {
#pragma unroll
        for (int i = 0; i < 8; ++i) r[i] = di * acc[i];
    }
    if (RELU) {
#pragma unroll
        for (int i = 0; i < 8; ++i) r[i] = fmaxf(r[i], 0.f);
    }
    float4 o0 = {r[0], r[1], r[2], r[3]};
    float4 o1 = {r[4], r[5], r[6], r[7]};
    float4* op = (float4*)(out + (size_t)node * D + c * 8);
    op[0] = o0;
    op[1] = o1;
}

// ------------------------------ pool + MLP ---------------------------------
__global__ __launch_bounds__(256) void k_pool(const float* __restrict__ h,
                                              const int* __restrict__ batch,
                                              float* __restrict__ g, int n) {
    __shared__ int se[2];
    __shared__ float red[8][32];
    int gi = blockIdx.x;
    int t = threadIdx.x;
    if (t == 0) {
        int lo = 0, hi = n;
        while (lo < hi) { int m = (lo + hi) >> 1; if (batch[m] < gi) lo = m + 1; else hi = m; }
        se[0] = lo;
        lo = 0; hi = n;
        while (lo < hi) { int m = (lo + hi) >> 1; if (batch[m] < gi + 1) lo = m + 1; else hi = m; }
        se[1] = lo;
    }
    __syncthreads();
    int start = se[0], end = se[1];
    int col = t & 31, sub = t >> 5;
    float acc = 0.f;
    for (int i = start + sub; i < end; i += 8)
        acc += h[(size_t)i * 32 + col];
    red[sub][col] = acc;
    __syncthreads();
    if (t < 32) {
        float s = 0.f;
#pragma unroll
        for (int q = 0; q < 8; ++q) s += red[q][t];
        float c = (float)(end - start);
        g[gi * 32 + t] = s / fmaxf(c, 1.0f);
    }
}

template <int K, int O, bool RELU>
__global__ void k_mlp(const float* __restrict__ in, const float* __restrict__ W,
                      const float* __restrict__ b, float* __restrict__ out, int G) {
    int gid = blockIdx.x * blockDim.x + threadIdx.x;
    if (gid >= G * O) return;
    int g = gid / O, j = gid % O;
    float s = b[j];
    for (int k = 0; k < K; ++k) s += in[g * K + k] * W[k * O + j];
    if (RELU) s = fmaxf(s, 0.f);
    out[gid] = s;
}

// ------------------------------- launch ------------------------------------
extern "C" void kernel_launch(void* const* d_in, const int* in_sizes, int n_in,
                              void* d_out, int out_size, void* d_ws, size_t ws_size,
                              hipStream_t stream) {
    const float* x    = (const float*)d_in[0];
    const int*   ei   = (const int*)d_in[1];
    const int*   batch= (const int*)d_in[2];
    const float* W1 = (const float*)d_in[3];  const float* b1 = (const float*)d_in[4];
    const float* W2 = (const float*)d_in[5];  const float* b2 = (const float*)d_in[6];
    const float* W3 = (const float*)d_in[7];  const float* b3 = (const float*)d_in[8];
    const float* W4 = (const float*)d_in[9];  const float* b4 = (const float*)d_in[10];
    const float* Wo = (const float*)d_in[11]; const float* bo = (const float*)d_in[12];
    const float* M1w = (const float*)d_in[13]; const float* M1b = (const float*)d_in[14];
    const float* M2w = (const float*)d_in[15]; const float* M2b = (const float*)d_in[16];
    const float* M3w = (const float*)d_in[17]; const float* M3b = (const float*)d_in[18];

    const int N = in_sizes[0] / 64;   // 100000
    const int E = in_sizes[1] / 2;    // 1600000
    const int G = out_size / 8;       // 64
    const int* src  = ei;
    const int* dstp = ei + E;

    // workspace layout (aliased where lifetimes are disjoint)
    char* w = (char*)d_ws;
    float* A   = (float*)w;                    // N*128 fp32 = 51.2MB (activations)
    unsigned short* xs = (unsigned short*)w;   //   aliased: N*64 bf16 (dead after layer-1 gather)
    w += (size_t)N * 128 * 4;
    float* agg = (float*)w;                    // N*64 fp32 = 25.6MB (layer-1 agg)
    unsigned short* hsb = (unsigned short*)w;  //   aliased: N*128 bf16 (layers 2-5 tables)
    w += (size_t)N * 128 * 2;
    int*   csr    = (int*)w;   w += (size_t)E * 4;
    int*   cnt    = (int*)w;   w += (size_t)N * 4;
    int*   rowptr = (int*)w;   w += (size_t)(N + 4) * 4;
    int*   fillc  = (int*)w;   w += (size_t)N * 4;
    int*   bsum   = (int*)w;   w += 4096;
    int*   bscan  = (int*)w;   w += 4096;
    float* dinv   = (float*)w; w += (size_t)N * 4;
    float* gp     = (float*)w; w += 64 * 32 * 4;
    float* m1     = (float*)w; w += 64 * 64 * 4;
    float* m2     = (float*)w; w += 64 * 16 * 4;

    const int NB = (N + TPB - 1) / TPB;
    const int EB = (E + TPB - 1) / TPB;

    hipMemsetAsync(cnt, 0, (size_t)N * 4, stream);
    hipMemsetAsync(fillc, 0, (size_t)N * 4, stream);
    k_count<<<EB, TPB, 0, stream>>>(dstp, cnt, E);
    k_scanA<<<NB, TPB, 0, stream>>>(cnt, rowptr, bsum, N);
    k_scanB<<<1, 512, 0, stream>>>(bsum, bscan, NB);
    k_scanC<<<NB, TPB, 0, stream>>>(rowptr, bscan, N);
    k_dinv<<<NB, TPB, 0, stream>>>(cnt, dinv, N);
    k_fill<<<EB, TPB, 0, stream>>>(src, dstp, rowptr, fillc, csr, E);

    // Layer 1 (aggregate-first on 64-dim): xs = bf16(x*dinv); agg = dinv*(sum);
    // A = relu(agg@W1 + b1)
    k_castx<<<(N * 8 + 255) / 256, 256, 0, stream>>>(x, dinv, xs, N);
    k_gather_bf<64, false, false><<<(N * 8 + 255) / 256, 256, 0, stream>>>(
        xs, rowptr, csr, dinv, nullptr, agg, N);
    k_gemm<64, 128, 1><<<(N + 127) / 128, 256, 0, stream>>>(agg, W1, nullptr, b1, A, N);

    // Layers 2-4: hsb = bf16((A@W)*dinv); A = relu(dinv*(gather) + b)
    k_gemm<128, 128, 0><<<(N + 127) / 128, 256, 0, stream>>>(A, W2, dinv, nullptr, hsb, N);
    k_gather_bf<128, true, true><<<(N * 16 + 255) / 256, 256, 0, stream>>>(
        hsb, rowptr, csr, dinv, b2, A, N);
    k_gemm<128, 128, 0><<<(N + 127) / 128, 256, 0, stream>>>(A, W3, dinv, nullptr, hsb, N);
    k_gather_bf<128, true, true><<<(N * 16 + 255) / 256, 256, 0, stream>>>(
        hsb, rowptr, csr, dinv, b3, A, N);
    k_gemm<128, 128, 0><<<(N + 127) / 128, 256, 0, stream>>>(A, W4, dinv, nullptr, hsb, N);
    k_gather_bf<128, true, true><<<(N * 16 + 255) / 256, 256, 0, stream>>>(
        hsb, rowptr, csr, dinv, b4, A, N);

    // Layer 5: 128 -> 32, no relu
    k_gemm<128, 32, 0><<<(N + 255) / 256, 256, 0, stream>>>(A, Wo, dinv, nullptr, hsb, N);
    k_gather_bf<32, false, true><<<(N * 4 + 255) / 256, 256, 0, stream>>>(
        hsb, rowptr, csr, dinv, bo, A, N);

    // Mean pool + MLP head
    k_pool<<<G, 256, 0, stream>>>(A, batch, gp, N);
    k_mlp<32, 64, true><<<(G * 64 + 255) / 256, 256, 0, stream>>>(gp, M1w, M1b, m1, G);
    k_mlp<64, 16, true><<<(G * 16 + 255) / 256, 256, 0, stream>>>(m1, M2w, M2b, m2, G);
    k_mlp<16, 8, false><<<(G * 8 + 255) / 256, 256, 0, stream>>>(m2, M3w, M3b, (float*)d_out, G);
}